// Round 6
// baseline (218.825 us; speedup 1.0000x reference)
//
#include <hip/hip_runtime.h>
#include <hip/hip_bf16.h>

// MultiHeadAttention: B=4, S=2048, D_MODEL=512, N_HEAD=8, D_K=64
// Pipeline: proj3 (Q*log2e/8, K, V->transposed fused), flash_attn (LDS-staged lockstep), out_gemm

typedef __attribute__((ext_vector_type(8))) short short8;
typedef __attribute__((ext_vector_type(4))) float f32x4;
typedef __attribute__((ext_vector_type(16))) float f32x16;
typedef __attribute__((ext_vector_type(4))) unsigned short u16x4;

static __device__ __forceinline__ unsigned short f2bf(float x) {
  union { float f; unsigned u; } v; v.f = x;
  unsigned r = v.u + 0x7fffu + ((v.u >> 16) & 1u);  // round-to-nearest-even
  return (unsigned short)(r >> 16);
}

static __device__ __forceinline__ short8 ld8(const unsigned short* p) {
  return *reinterpret_cast<const short8*>(p);
}

static __device__ __forceinline__ float vmax3(float a, float b, float c) {
  float r; asm("v_max3_f32 %0, %1, %2, %3" : "=v"(r) : "v"(a), "v"(b), "v"(c)); return r;
}

static __device__ __forceinline__ float vexp2(float x) {
  float r; asm("v_exp_f32 %0, %1" : "=v"(r) : "v"(x)); return r;
}

// P(16 f32, rows r(i,hi)) -> two bf16 B-fragments (16-kv groups) via
// cvt_pk + shfl_xor(32) + select. Verified round 4.
static __device__ __forceinline__ void repack(const float* p, int hi,
                                              short8& f0, short8& f1) {
  int pk[8];
#pragma unroll
  for (int i = 0; i < 8; ++i)
    asm("v_cvt_pk_bf16_f32 %0, %1, %2" : "=v"(pk[i]) : "v"(p[2 * i]), "v"(p[2 * i + 1]));
  int x0 = __shfl_xor(pk[0], 32), x1 = __shfl_xor(pk[1], 32);
  int x2 = __shfl_xor(pk[2], 32), x3 = __shfl_xor(pk[3], 32);
  int x4 = __shfl_xor(pk[4], 32), x5 = __shfl_xor(pk[5], 32);
  int x6 = __shfl_xor(pk[6], 32), x7 = __shfl_xor(pk[7], 32);
  union { int w[4]; short8 v; } a, b;
  a.w[0] = hi ? x2 : pk[0];
  a.w[1] = hi ? x3 : pk[1];
  a.w[2] = hi ? pk[2] : x0;
  a.w[3] = hi ? pk[3] : x1;
  b.w[0] = hi ? x6 : pk[4];
  b.w[1] = hi ? x7 : pk[5];
  b.w[2] = hi ? pk[6] : x4;
  b.w[3] = hi ? pk[7] : x5;
  f0 = a.v; f1 = b.v;
}

// ---------------------------------------------------------------------------
// Fused projection GEMMs: z = blockIdx.z selects {Q, K, V}.
// Q gets oscale = (1/8)*log2(e) so flash softmax uses exp2 directly.
// V (z==2) written transposed [b*8+h][d][s].
// ---------------------------------------------------------------------------
__global__ __launch_bounds__(256) void proj3(
    const float* __restrict__ Xq, const float* __restrict__ Xk, const float* __restrict__ Xv,
    const float* __restrict__ Wq, const float* __restrict__ Wk, const float* __restrict__ Wv,
    const float* __restrict__ bq, const float* __restrict__ bk, const float* __restrict__ bv,
    unsigned short* __restrict__ Qh, unsigned short* __restrict__ Kh,
    unsigned short* __restrict__ Vt)
{
  const int z = blockIdx.z;
  const float* X = z == 0 ? Xq : z == 1 ? Xk : Xv;
  const float* W = z == 0 ? Wq : z == 1 ? Wk : Wv;
  const float* bias = z == 0 ? bq : z == 1 ? bk : bv;
  unsigned short* dst = z == 0 ? Qh : z == 1 ? Kh : Vt;
  const int vmode = (z == 2);
  const float oscale = z == 0 ? 0.1803368801f : 1.0f;  // (1/8)*log2(e)

  __shared__ unsigned short Al[128][40];
  __shared__ unsigned short Bl[128][40];
  const int tid = threadIdx.x;
  const int lane = tid & 63;
  const int g = lane >> 4, c = lane & 15;
  const int wave = tid >> 6;
  const int m0 = blockIdx.x * 128, n0 = blockIdx.y * 128;
  const int wm = (wave & 1) * 64, wn = (wave >> 1) * 64;
  f32x4 acc[4][4] = {};

  const int srow = tid >> 3;
  const int scol = (tid & 7) * 4;

  for (int k0 = 0; k0 < 512; k0 += 32) {
    __syncthreads();
#pragma unroll
    for (int p = 0; p < 4; ++p) {
      int row = p * 32 + srow;
      f32x4 xv = *reinterpret_cast<const f32x4*>(&X[(size_t)(m0 + row) * 512 + k0 + scol]);
      u16x4 xb = { f2bf(xv[0]), f2bf(xv[1]), f2bf(xv[2]), f2bf(xv[3]) };
      *reinterpret_cast<u16x4*>(&Al[row][scol]) = xb;
      f32x4 wv = *reinterpret_cast<const f32x4*>(&W[(size_t)(n0 + row) * 512 + k0 + scol]);
      u16x4 wb = { f2bf(wv[0]), f2bf(wv[1]), f2bf(wv[2]), f2bf(wv[3]) };
      *reinterpret_cast<u16x4*>(&Bl[row][scol]) = wb;
    }
    __syncthreads();
    short8 af[4], bfr[4];
#pragma unroll
    for (int i = 0; i < 4; ++i) {
      af[i]  = ld8(&Al[wm + i * 16 + c][g * 8]);
      bfr[i] = ld8(&Bl[wn + i * 16 + c][g * 8]);
    }
#pragma unroll
    for (int i = 0; i < 4; ++i)
#pragma unroll
      for (int j = 0; j < 4; ++j)
        acc[i][j] = __builtin_amdgcn_mfma_f32_16x16x32_bf16(af[i], bfr[j], acc[i][j], 0, 0, 0);
  }

#pragma unroll
  for (int j = 0; j < 4; ++j) {
    int col = n0 + wn + j * 16 + c;
    float bcol = bias[col];
    int h = col >> 6, d = col & 63;
#pragma unroll
    for (int i = 0; i < 4; ++i) {
#pragma unroll
      for (int r = 0; r < 4; ++r) {
        int row = m0 + wm + i * 16 + g * 4 + r;
        int b = row >> 11, s = row & 2047;
        float val = (acc[i][j][r] + bcol) * oscale;
        size_t idx = vmode ? ((size_t)((b * 8 + h) * 64 + d) * 2048 + s)
                           : ((size_t)((b * 8 + h) * 2048 + s) * 64 + d);
        dst[idx] = f2bf(val);
      }
    }
  }
}

// ---------------------------------------------------------------------------
// Flash attention, LDS-staged lockstep. Block = 4 waves, each owns a 32-row
// q-tile (128 q-rows/block); ALL waves share the same kv tile staged in LDS
// (double-buffered, reg-prefetched: LOADS issued one full compute phase ahead,
// STORES after barrier). KVBLK=64. No split-KV merge.
// Per wave per step: S^T = mfma(K,Q) x8 -> 32 scores/lane in regs; lane-local
// softmax in log2 domain (Q pre-scaled log2e/8), defer-max THR=11; repack p
// (cvt_pk+shfl, r4-verified) -> 4 B-frags; PV: O^T += mfma(V^T, P) x8.
// LDS tiles padded [64][68] (136B rows -> 2-way banks = free).
// ---------------------------------------------------------------------------
__global__ __launch_bounds__(256) void flash_attn(
    const unsigned short* __restrict__ Qh, const unsigned short* __restrict__ Kh,
    const unsigned short* __restrict__ Vt, unsigned short* __restrict__ attn)
{
  __shared__ unsigned short Kl[2][64][68];
  __shared__ unsigned short Vl[2][64][68];
  const int tid = threadIdx.x;
  const int lane = tid & 63;
  const int wave = tid >> 6;
  const int lq = lane & 31, hi = lane >> 5;
  const int bh = blockIdx.y;
  const int q0 = blockIdx.x * 128 + wave * 32;
  const unsigned short* Qp = Qh + (size_t)bh * 2048 * 64;
  const unsigned short* Kp = Kh + (size_t)bh * 2048 * 64;
  const unsigned short* Vp = Vt + (size_t)bh * 64 * 2048;

  // staging geometry: 256 threads cover a [64][64] bf16 tile in two row-halves
  const int srow = tid >> 3;          // 0..31
  const int scol = (tid & 7) * 8;     // 0..56 step 8 (16B)

  short8 kr0, kr1, vr0, vr1;
#define FA_LOADS(kv0)                                                     \
  kr0 = ld8(Kp + (size_t)((kv0) + srow) * 64 + scol);                     \
  kr1 = ld8(Kp + (size_t)((kv0) + 32 + srow) * 64 + scol);                \
  vr0 = ld8(Vp + (size_t)srow * 2048 + (kv0) + scol);                     \
  vr1 = ld8(Vp + (size_t)(32 + srow) * 2048 + (kv0) + scol);
#define FA_STORES(b)                                                      \
  *reinterpret_cast<short8*>(&Kl[b][srow][scol]) = kr0;                   \
  *reinterpret_cast<short8*>(&Kl[b][32 + srow][scol]) = kr1;              \
  *reinterpret_cast<short8*>(&Vl[b][srow][scol]) = vr0;                   \
  *reinterpret_cast<short8*>(&Vl[b][32 + srow][scol]) = vr1;

  // Q B-fragments: col=lq, k=d = ds*16 + hi*8 + j
  short8 qf[4];
#pragma unroll
  for (int ds = 0; ds < 4; ++ds)
    qf[ds] = ld8(Qp + (size_t)(q0 + lq) * 64 + ds * 16 + hi * 8);

  f32x16 acc0 = {}, acc1 = {};
  float mrun = -1e30f, lrun = 0.f;

  FA_LOADS(0);
  FA_STORES(0);
  FA_LOADS(64);
  __syncthreads();

  for (int t = 0; t < 32; ++t) {
    const int cb = t & 1;

    // ---- QK^T: S^T[kv][q], two 32-kv sub-tiles ----
    f32x16 sp0 = {}, sp1 = {};
#pragma unroll
    for (int ds = 0; ds < 4; ++ds) {
      short8 k0 = ld8(&Kl[cb][lq][ds * 16 + hi * 8]);
      sp0 = __builtin_amdgcn_mfma_f32_32x32x16_bf16(k0, qf[ds], sp0, 0, 0, 0);
    }
#pragma unroll
    for (int ds = 0; ds < 4; ++ds) {
      short8 k1 = ld8(&Kl[cb][32 + lq][ds * 16 + hi * 8]);
      sp1 = __builtin_amdgcn_mfma_f32_32x32x16_bf16(k1, qf[ds], sp1, 0, 0, 0);
    }

    // ---- online softmax (log2 domain) over 32 lane-local scores ----
    float ta = vmax3(sp0[0], sp0[1], sp0[2]);
    float tb = vmax3(sp0[3], sp0[4], sp0[5]);
    float tc = vmax3(sp0[6], sp0[7], sp0[8]);
    float td = vmax3(sp0[9], sp0[10], sp0[11]);
    ta = vmax3(ta, sp0[12], sp0[13]);
    tb = vmax3(tb, sp0[14], sp0[15]);
    tc = vmax3(tc, sp1[0], sp1[1]);
    td = vmax3(td, sp1[2], sp1[3]);
    ta = vmax3(ta, sp1[4], sp1[5]);
    tb = vmax3(tb, sp1[6], sp1[7]);
    tc = vmax3(tc, sp1[8], sp1[9]);
    td = vmax3(td, sp1[10], sp1[11]);
    ta = vmax3(ta, sp1[12], sp1[13]);
    tb = vmax3(tb, sp1[14], sp1[15]);
    float tm = vmax3(ta, tb, vmax3(tc, td, ta));
    float tmx = fmaxf(tm, __shfl_xor(tm, 32));
    if (!__all(tmx <= mrun + 11.0f)) {   // defer-max: P bounded by 2^11
      float mn = fmaxf(mrun, tmx);
      float alpha = vexp2(mrun - mn);
      mrun = mn;
      lrun *= alpha;
#pragma unroll
      for (int i = 0; i < 16; ++i) { acc0[i] *= alpha; acc1[i] *= alpha; }
    }
    float p0[16], p1[16];
    float ls = 0.f;
#pragma unroll
    for (int i = 0; i < 16; ++i) { p0[i] = vexp2(sp0[i] - mrun); ls += p0[i]; }
#pragma unroll
    for (int i = 0; i < 16; ++i) { p1[i] = vexp2(sp1[i] - mrun); ls += p1[i]; }
    lrun += ls + __shfl_xor(ls, 32);

    // ---- P -> bf16 B-fragments (4 x 16-kv groups) ----
    short8 pf0, pf1, pf2, pf3;
    repack(p0, hi, pf0, pf1);
    repack(p1, hi, pf2, pf3);

    // ---- PV: O^T[d][q] += V^T-frag x P-frag ----
    {
      short8 va = ld8(&Vl[cb][lq][0 + hi * 8]);
      short8 vb = ld8(&Vl[cb][32 + lq][0 + hi * 8]);
      acc0 = __builtin_amdgcn_mfma_f32_32x32x16_bf16(va, pf0, acc0, 0, 0, 0);
      acc1 = __builtin_amdgcn_mfma_f32_32x32x16_bf16(vb, pf0, acc1, 0, 0, 0);
      va = ld8(&Vl[cb][lq][16 + hi * 8]);
      vb = ld8(&Vl[cb][32 + lq][16 + hi * 8]);
      acc0 = __builtin_amdgcn_mfma_f32_32x32x16_bf16(va, pf1, acc0, 0, 0, 0);
      acc1 = __builtin_amdgcn_mfma_f32_32x32x16_bf16(vb, pf1, acc1, 0, 0, 0);
      va = ld8(&Vl[cb][lq][32 + hi * 8]);
      vb = ld8(&Vl[cb][32 + lq][32 + hi * 8]);
      acc0 = __builtin_amdgcn_mfma_f32_32x32x16_bf16(va, pf2, acc0, 0, 0, 0);
      acc1 = __builtin_amdgcn_mfma_f32_32x32x16_bf16(vb, pf2, acc1, 0, 0, 0);
      va = ld8(&Vl[cb][lq][48 + hi * 8]);
      vb = ld8(&Vl[cb][32 + lq][48 + hi * 8]);
      acc0 = __builtin_amdgcn_mfma_f32_32x32x16_bf16(va, pf3, acc0, 0, 0, 0);
      acc1 = __builtin_amdgcn_mfma_f32_32x32x16_bf16(vb, pf3, acc1, 0, 0, 0);
    }

    if (t < 31) {
      __syncthreads();                 // all waves done reading buf cb
      FA_STORES(cb ^ 1);               // stage tile t+1
      if (t < 30) { FA_LOADS((t + 2) * 64); }
      __syncthreads();                 // tile t+1 visible
    }
  }

  // ---- epilogue: per-wave, no merge ----
  {
    float rl = 1.0f / lrun;
    const int b = bh >> 3, h = bh & 7;
    unsigned short* base = attn + ((size_t)(b * 2048 + q0 + lq)) * 512 + h * 64;
#pragma unroll
    for (int g = 0; g < 4; ++g) {
      u16x4 oa, ob;
#pragma unroll
      for (int j = 0; j < 4; ++j) {
        oa[j] = f2bf(acc0[4 * g + j] * rl);
        ob[j] = f2bf(acc1[4 * g + j] * rl);
      }
      *reinterpret_cast<u16x4*>(base + 8 * g + 4 * hi) = oa;
      *reinterpret_cast<u16x4*>(base + 32 + 8 * g + 4 * hi) = ob;
    }
  }
#undef FA_LOADS
#undef FA_STORES
}

// ---------------------------------------------------------------------------
// Output projection: out(fp32) = attn(bf16)[8192,512] @ W_o^T + b_o
// ---------------------------------------------------------------------------
__global__ __launch_bounds__(256) void out_gemm(
    const unsigned short* __restrict__ A, const float* __restrict__ W,
    const float* __restrict__ bias, float* __restrict__ out)
{
  __shared__ unsigned short Al[128][40];
  __shared__ unsigned short Bl[128][40];
  const int tid = threadIdx.x;
  const int lane = tid & 63;
  const int g = lane >> 4, c = lane & 15;
  const int wave = tid >> 6;
  const int m0 = blockIdx.x * 128, n0 = blockIdx.y * 128;
  const int wm = (wave & 1) * 64, wn = (wave >> 1) * 64;
  f32x4 acc[4][4] = {};

  const int arow = tid >> 2;
  const int acol = (tid & 3) * 8;
  const int srow = tid >> 3;
  const int scol = (tid & 7) * 4;

  for (int k0 = 0; k0 < 512; k0 += 32) {
    __syncthreads();
#pragma unroll
    for (int p = 0; p < 2; ++p) {
      int row = p * 64 + arow;
      short8 av = ld8(&A[(size_t)(m0 + row) * 512 + k0 + acol]);
      *reinterpret_cast<short8*>(&Al[row][acol]) = av;
    }
#pragma unroll
    for (int p = 0; p < 4; ++p) {
      int row = p * 32 + srow;
      f32x4 wv = *reinterpret_cast<const f32x4*>(&W[(size_t)(n0 + row) * 512 + k0 + scol]);
      u16x4 wb = { f2bf(wv[0]), f2bf(wv[1]), f2bf(wv[2]), f2bf(wv[3]) };
      *reinterpret_cast<u16x4*>(&Bl[row][scol]) = wb;
    }
    __syncthreads();
    short8 af[4], bfr[4];
#pragma unroll
    for (int i = 0; i < 4; ++i) {
      af[i]  = ld8(&Al[wm + i * 16 + c][g * 8]);
      bfr[i] = ld8(&Bl[wn + i * 16 + c][g * 8]);
    }
#pragma unroll
    for (int i = 0; i < 4; ++i)
#pragma unroll
      for (int j = 0; j < 4; ++j)
        acc[i][j] = __builtin_amdgcn_mfma_f32_16x16x32_bf16(af[i], bfr[j], acc[i][j], 0, 0, 0);
  }

#pragma unroll
  for (int j = 0; j < 4; ++j) {
    int col = n0 + wn + j * 16 + c;
    float bcol = bias[col];
#pragma unroll
    for (int i = 0; i < 4; ++i)
#pragma unroll
      for (int r = 0; r < 4; ++r) {
        int row = m0 + wm + i * 16 + g * 4 + r;
        out[(size_t)row * 512 + col] = acc[i][j][r] + bcol;
      }
  }
}

extern "C" void kernel_launch(void* const* d_in, const int* in_sizes, int n_in,
                              void* d_out, int out_size, void* d_ws, size_t ws_size,
                              hipStream_t stream)
{
  const float* q  = (const float*)d_in[0];
  const float* k  = (const float*)d_in[1];
  const float* v  = (const float*)d_in[2];
  const float* Wq = (const float*)d_in[3];
  const float* bq = (const float*)d_in[4];
  const float* Wk = (const float*)d_in[5];
  const float* bk = (const float*)d_in[6];
  const float* Wv = (const float*)d_in[7];
  const float* bv = (const float*)d_in[8];
  const float* Wo = (const float*)d_in[9];
  const float* bo = (const float*)d_in[10];
  float* out = (float*)d_out;

  unsigned short* ws = (unsigned short*)d_ws;
  unsigned short* Qh = ws;                              // [32][2048][64] (pre-scaled log2e/8)
  unsigned short* Kh = ws + (size_t)4 * 1024 * 1024;    // [32][2048][64]
  unsigned short* Vt = ws + (size_t)8 * 1024 * 1024;    // [32][64][2048]
  unsigned short* at = ws + (size_t)12 * 1024 * 1024;   // [4][2048][512]

  dim3 blk(256);
  proj3<<<dim3(64, 4, 3), blk, 0, stream>>>(q, k, v, Wq, Wk, Wv, bq, bk, bv, Qh, Kh, Vt);
  flash_attn<<<dim3(16, 32), blk, 0, stream>>>(Qh, Kh, Vt, at);
  out_gemm<<<dim3(64, 4), blk, 0, stream>>>(at, Wo, bo, out);
}

// Round 7
// 195.406 us; speedup vs baseline: 1.1198x; 1.1198x over previous
//
#include <hip/hip_runtime.h>
#include <hip/hip_bf16.h>

// MultiHeadAttention: B=4, S=2048, D_MODEL=512, N_HEAD=8, D_K=64
// Pipeline: proj3 (Q*log2e/8, K, V->transposed fused), flash_attn (shfl-free repack), out_gemm

typedef __attribute__((ext_vector_type(8))) short short8;
typedef __attribute__((ext_vector_type(4))) float f32x4;
typedef __attribute__((ext_vector_type(16))) float f32x16;
typedef __attribute__((ext_vector_type(4))) unsigned short u16x4;

static __device__ __forceinline__ unsigned short f2bf(float x) {
  union { float f; unsigned u; } v; v.f = x;
  unsigned r = v.u + 0x7fffu + ((v.u >> 16) & 1u);  // round-to-nearest-even
  return (unsigned short)(r >> 16);
}

static __device__ __forceinline__ short8 ld8(const unsigned short* p) {
  return *reinterpret_cast<const short8*>(p);
}

static __device__ __forceinline__ float vmax3(float a, float b, float c) {
  float r; asm("v_max3_f32 %0, %1, %2, %3" : "=v"(r) : "v"(a), "v"(b), "v"(c)); return r;
}

static __device__ __forceinline__ float vexp2(float x) {
  float r; asm("v_exp_f32 %0, %1" : "=v"(r) : "v"(x)); return r;
}

static __device__ __forceinline__ int cvtpk(float a, float b) {
  int r; asm("v_cvt_pk_bf16_f32 %0, %1, %2" : "=v"(r) : "v"(a), "v"(b)); return r;
}

// ---------------------------------------------------------------------------
// Fused projection GEMMs: z = blockIdx.z selects {Q, K, V}.
// Q gets oscale = (1/8)*log2(e) so flash softmax uses exp2 directly.
// V (z==2) written transposed [b*8+h][d][s].
// ---------------------------------------------------------------------------
__global__ __launch_bounds__(256) void proj3(
    const float* __restrict__ Xq, const float* __restrict__ Xk, const float* __restrict__ Xv,
    const float* __restrict__ Wq, const float* __restrict__ Wk, const float* __restrict__ Wv,
    const float* __restrict__ bq, const float* __restrict__ bk, const float* __restrict__ bv,
    unsigned short* __restrict__ Qh, unsigned short* __restrict__ Kh,
    unsigned short* __restrict__ Vt)
{
  const int z = blockIdx.z;
  const float* X = z == 0 ? Xq : z == 1 ? Xk : Xv;
  const float* W = z == 0 ? Wq : z == 1 ? Wk : Wv;
  const float* bias = z == 0 ? bq : z == 1 ? bk : bv;
  unsigned short* dst = z == 0 ? Qh : z == 1 ? Kh : Vt;
  const int vmode = (z == 2);
  const float oscale = z == 0 ? 0.1803368801f : 1.0f;  // (1/8)*log2(e)

  __shared__ unsigned short Al[128][40];
  __shared__ unsigned short Bl[128][40];
  const int tid = threadIdx.x;
  const int lane = tid & 63;
  const int g = lane >> 4, c = lane & 15;
  const int wave = tid >> 6;
  const int m0 = blockIdx.x * 128, n0 = blockIdx.y * 128;
  const int wm = (wave & 1) * 64, wn = (wave >> 1) * 64;
  f32x4 acc[4][4] = {};

  const int srow = tid >> 3;
  const int scol = (tid & 7) * 4;

  for (int k0 = 0; k0 < 512; k0 += 32) {
    __syncthreads();
#pragma unroll
    for (int p = 0; p < 4; ++p) {
      int row = p * 32 + srow;
      f32x4 xv = *reinterpret_cast<const f32x4*>(&X[(size_t)(m0 + row) * 512 + k0 + scol]);
      u16x4 xb = { f2bf(xv[0]), f2bf(xv[1]), f2bf(xv[2]), f2bf(xv[3]) };
      *reinterpret_cast<u16x4*>(&Al[row][scol]) = xb;
      f32x4 wv = *reinterpret_cast<const f32x4*>(&W[(size_t)(n0 + row) * 512 + k0 + scol]);
      u16x4 wb = { f2bf(wv[0]), f2bf(wv[1]), f2bf(wv[2]), f2bf(wv[3]) };
      *reinterpret_cast<u16x4*>(&Bl[row][scol]) = wb;
    }
    __syncthreads();
    short8 af[4], bfr[4];
#pragma unroll
    for (int i = 0; i < 4; ++i) {
      af[i]  = ld8(&Al[wm + i * 16 + c][g * 8]);
      bfr[i] = ld8(&Bl[wn + i * 16 + c][g * 8]);
    }
#pragma unroll
    for (int i = 0; i < 4; ++i)
#pragma unroll
      for (int j = 0; j < 4; ++j)
        acc[i][j] = __builtin_amdgcn_mfma_f32_16x16x32_bf16(af[i], bfr[j], acc[i][j], 0, 0, 0);
  }

#pragma unroll
  for (int j = 0; j < 4; ++j) {
    int col = n0 + wn + j * 16 + c;
    float bcol = bias[col];
    int h = col >> 6, d = col & 63;
#pragma unroll
    for (int i = 0; i < 4; ++i) {
#pragma unroll
      for (int r = 0; r < 4; ++r) {
        int row = m0 + wm + i * 16 + g * 4 + r;
        int b = row >> 11, s = row & 2047;
        float val = (acc[i][j][r] + bcol) * oscale;
        size_t idx = vmode ? ((size_t)((b * 8 + h) * 64 + d) * 2048 + s)
                           : ((size_t)((b * 8 + h) * 2048 + s) * 64 + d);
        dst[idx] = f2bf(val);
      }
    }
  }
}

// ---------------------------------------------------------------------------
// Flash attention, swapped-QK 32x32, 4-way KV split, SHFL-FREE P repack.
// Key trick: K A-frag row j is loaded from kv index b32(j) (swap bits 2<->3
// of the row index; b is an involution). Then S^T rows are born such that
// cvt_pk(p[2w],p[2w+1]) IS the PV B-fragment word directly -- the 8 cross-
// lane exchanges per 32 kv are gone. V is loaded unpermuted/contiguous.
// Softmax: 2 shfl_xor(32) per 64 kv (max, sum), log2 domain, defer-max THR=11.
// Per wave: kv quarter of 512, 8 iterations of KVBLK=64; K(t+1) loads issued
// after QK(t), V(t+1) after PV(t) so softmax/PV hides global latency.
// ---------------------------------------------------------------------------
__global__ __launch_bounds__(256) void flash_attn(
    const unsigned short* __restrict__ Qh, const unsigned short* __restrict__ Kh,
    const unsigned short* __restrict__ Vt, unsigned short* __restrict__ attn)
{
  __shared__ float Mred[4][32];
  __shared__ float Lred[4][32];
  __shared__ float AccO[2][64][32];   // [stage][d][q]
  const int lane = threadIdx.x & 63;
  const int kh = threadIdx.x >> 6;    // kv quarter
  const int lq = lane & 31;           // q column / frag row
  const int hi = lane >> 5;           // lane half
  const int bh = blockIdx.y;
  const int q0 = blockIdx.x * 32;
  const unsigned short* Qp = Qh + (size_t)bh * 2048 * 64;
  const unsigned short* Kp = Kh + (size_t)bh * 2048 * 64;
  const unsigned short* Vp = Vt + (size_t)bh * 64 * 2048;
  const int blq = (lq & 19) | ((lq & 4) << 1) | ((lq & 8) >> 1);  // swap bits 2,3

  // Q B-fragments: col=lq, k=d = ds*16 + hi*8 + j
  short8 qf[4];
#pragma unroll
  for (int ds = 0; ds < 4; ++ds)
    qf[ds] = ld8(Qp + (size_t)(q0 + lq) * 64 + ds * 16 + hi * 8);

  // row/col bases for this wave's kv quarter
  const unsigned short* Kb  = Kp + (size_t)(kh * 512 + blq) * 64 + hi * 8;
  const unsigned short* Vb0 = Vp + (size_t)lq * 2048        + kh * 512 + hi * 8;
  const unsigned short* Vb1 = Vp + (size_t)(32 + lq) * 2048 + kh * 512 + hi * 8;

  short8 kf[8], vf[8];
#define LOADK(t) do {                                                       \
    const unsigned short* kp_ = Kb + (size_t)(t) * 64 * 64;                 \
    kf[0] = ld8(kp_ +  0); kf[1] = ld8(kp_ + 16);                           \
    kf[2] = ld8(kp_ + 32); kf[3] = ld8(kp_ + 48);                           \
    kp_ += 32 * 64;                                                         \
    kf[4] = ld8(kp_ +  0); kf[5] = ld8(kp_ + 16);                           \
    kf[6] = ld8(kp_ + 32); kf[7] = ld8(kp_ + 48);                           \
  } while (0)
#define LOADV(t) do {                                                       \
    const unsigned short* vp_ = Vb0 + (t) * 64;                             \
    vf[0] = ld8(vp_ +  0); vf[2] = ld8(vp_ + 16);                           \
    vf[4] = ld8(vp_ + 32); vf[6] = ld8(vp_ + 48);                           \
    vp_ = Vb1 + (t) * 64;                                                   \
    vf[1] = ld8(vp_ +  0); vf[3] = ld8(vp_ + 16);                           \
    vf[5] = ld8(vp_ + 32); vf[7] = ld8(vp_ + 48);                           \
  } while (0)

  f32x16 acc0 = {}, acc1 = {};
  float mrun = -1e30f, lrun = 0.f;

  LOADK(0);
  LOADV(0);
#pragma unroll 2
  for (int t = 0; t < 8; ++t) {
    // ---- QK^T: two independent 32-kv chains ----
    f32x16 sp0 = {}, sp1 = {};
    sp0 = __builtin_amdgcn_mfma_f32_32x32x16_bf16(kf[0], qf[0], sp0, 0, 0, 0);
    sp1 = __builtin_amdgcn_mfma_f32_32x32x16_bf16(kf[4], qf[0], sp1, 0, 0, 0);
    sp0 = __builtin_amdgcn_mfma_f32_32x32x16_bf16(kf[1], qf[1], sp0, 0, 0, 0);
    sp1 = __builtin_amdgcn_mfma_f32_32x32x16_bf16(kf[5], qf[1], sp1, 0, 0, 0);
    sp0 = __builtin_amdgcn_mfma_f32_32x32x16_bf16(kf[2], qf[2], sp0, 0, 0, 0);
    sp1 = __builtin_amdgcn_mfma_f32_32x32x16_bf16(kf[6], qf[2], sp1, 0, 0, 0);
    sp0 = __builtin_amdgcn_mfma_f32_32x32x16_bf16(kf[3], qf[3], sp0, 0, 0, 0);
    sp1 = __builtin_amdgcn_mfma_f32_32x32x16_bf16(kf[7], qf[3], sp1, 0, 0, 0);

    if (t < 7) LOADK(t + 1);   // kf consumed; hide K(t+1) under softmax+PV

    // ---- online softmax (log2 domain) over 32 lane-local scores ----
    float ta = vmax3(sp0[0], sp0[1], sp0[2]);
    float tb = vmax3(sp0[3], sp0[4], sp0[5]);
    float tc = vmax3(sp0[6], sp0[7], sp0[8]);
    float td = vmax3(sp0[9], sp0[10], sp0[11]);
    ta = vmax3(ta, sp0[12], sp0[13]);
    tb = vmax3(tb, sp0[14], sp0[15]);
    tc = vmax3(tc, sp1[0], sp1[1]);
    td = vmax3(td, sp1[2], sp1[3]);
    ta = vmax3(ta, sp1[4], sp1[5]);
    tb = vmax3(tb, sp1[6], sp1[7]);
    tc = vmax3(tc, sp1[8], sp1[9]);
    td = vmax3(td, sp1[10], sp1[11]);
    ta = vmax3(ta, sp1[12], sp1[13]);
    tb = vmax3(tb, sp1[14], sp1[15]);
    float tm = fmaxf(vmax3(ta, tb, tc), td);
    float tmx = fmaxf(tm, __shfl_xor(tm, 32));
    if (!__all(tmx <= mrun + 11.0f)) {   // defer-max: P bounded by 2^11
      float mn = fmaxf(mrun, tmx);
      float alpha = vexp2(mrun - mn);
      mrun = mn;
      lrun *= alpha;
#pragma unroll
      for (int i = 0; i < 16; ++i) { acc0[i] *= alpha; acc1[i] *= alpha; }
    }
    float p0[16], p1[16];
    float ls = 0.f;
#pragma unroll
    for (int i = 0; i < 16; ++i) { p0[i] = vexp2(sp0[i] - mrun); ls += p0[i]; }
#pragma unroll
    for (int i = 0; i < 16; ++i) { p1[i] = vexp2(sp1[i] - mrun); ls += p1[i]; }
    lrun += ls + __shfl_xor(ls, 32);

    // ---- P -> bf16 B-fragments, NO cross-lane ops (K rows pre-permuted) ----
    union { int w[4]; short8 v; } pf0, pf1, pf2, pf3;
#pragma unroll
    for (int w = 0; w < 4; ++w) {
      pf0.w[w] = cvtpk(p0[2 * w],     p0[2 * w + 1]);
      pf1.w[w] = cvtpk(p0[8 + 2 * w], p0[9 + 2 * w]);
      pf2.w[w] = cvtpk(p1[2 * w],     p1[2 * w + 1]);
      pf3.w[w] = cvtpk(p1[8 + 2 * w], p1[9 + 2 * w]);
    }

    // ---- PV: O^T[d][q] += V^T x P, two independent d-chains ----
    acc0 = __builtin_amdgcn_mfma_f32_32x32x16_bf16(vf[0], pf0.v, acc0, 0, 0, 0);
    acc1 = __builtin_amdgcn_mfma_f32_32x32x16_bf16(vf[1], pf0.v, acc1, 0, 0, 0);
    acc0 = __builtin_amdgcn_mfma_f32_32x32x16_bf16(vf[2], pf1.v, acc0, 0, 0, 0);
    acc1 = __builtin_amdgcn_mfma_f32_32x32x16_bf16(vf[3], pf1.v, acc1, 0, 0, 0);
    acc0 = __builtin_amdgcn_mfma_f32_32x32x16_bf16(vf[4], pf2.v, acc0, 0, 0, 0);
    acc1 = __builtin_amdgcn_mfma_f32_32x32x16_bf16(vf[5], pf2.v, acc1, 0, 0, 0);
    acc0 = __builtin_amdgcn_mfma_f32_32x32x16_bf16(vf[6], pf3.v, acc0, 0, 0, 0);
    acc1 = __builtin_amdgcn_mfma_f32_32x32x16_bf16(vf[7], pf3.v, acc1, 0, 0, 0);

    if (t < 7) LOADV(t + 1);   // vf consumed; hide V(t+1) under next QK+softmax
  }
#undef LOADK
#undef LOADV

  // ---- 4-way merge via staged LDS accumulate ----
  if (lane < 32) { Mred[kh][lq] = mrun; Lred[kh][lq] = lrun; }
  __syncthreads();
  float m = fmaxf(fmaxf(Mred[0][lq], Mred[1][lq]), fmaxf(Mred[2][lq], Mred[3][lq]));
  float ltot = Lred[0][lq] * vexp2(Mred[0][lq] - m)
             + Lred[1][lq] * vexp2(Mred[1][lq] - m)
             + Lred[2][lq] * vexp2(Mred[2][lq] - m)
             + Lred[3][lq] * vexp2(Mred[3][lq] - m);
  float sc = vexp2(mrun - m);
#pragma unroll
  for (int i = 0; i < 16; ++i) { acc0[i] *= sc; acc1[i] *= sc; }
  if (kh >= 2) {
#pragma unroll
    for (int i = 0; i < 16; ++i) {
      int d = (i & 3) + 8 * (i >> 2) + 4 * hi;
      AccO[kh - 2][d][lq]      = acc0[i];
      AccO[kh - 2][32 + d][lq] = acc1[i];
    }
  }
  __syncthreads();
  if (kh < 2) {
#pragma unroll
    for (int i = 0; i < 16; ++i) {
      int d = (i & 3) + 8 * (i >> 2) + 4 * hi;
      AccO[kh][d][lq]      += acc0[i];
      AccO[kh][32 + d][lq] += acc1[i];
    }
  }
  __syncthreads();
  if (kh < 2) {
    float rl = 1.0f / ltot;
    const int b = bh >> 3, h = bh & 7;
    unsigned short* base = attn + ((size_t)(b * 2048 + q0 + lq)) * 512 + h * 64
                         + kh * 32 + hi * 16;
    union { unsigned short u[16]; short8 v[2]; } ov;
#pragma unroll
    for (int dd = 0; dd < 16; ++dd) {
      int d = kh * 32 + hi * 16 + dd;
      ov.u[dd] = f2bf((AccO[0][d][lq] + AccO[1][d][lq]) * rl);
    }
    *reinterpret_cast<short8*>(base) = ov.v[0];
    *reinterpret_cast<short8*>(base + 8) = ov.v[1];
  }
}

// ---------------------------------------------------------------------------
// Output projection: out(fp32) = attn(bf16)[8192,512] @ W_o^T + b_o
// ---------------------------------------------------------------------------
__global__ __launch_bounds__(256) void out_gemm(
    const unsigned short* __restrict__ A, const float* __restrict__ W,
    const float* __restrict__ bias, float* __restrict__ out)
{
  __shared__ unsigned short Al[128][40];
  __shared__ unsigned short Bl[128][40];
  const int tid = threadIdx.x;
  const int lane = tid & 63;
  const int g = lane >> 4, c = lane & 15;
  const int wave = tid >> 6;
  const int m0 = blockIdx.x * 128, n0 = blockIdx.y * 128;
  const int wm = (wave & 1) * 64, wn = (wave >> 1) * 64;
  f32x4 acc[4][4] = {};

  const int arow = tid >> 2;
  const int acol = (tid & 3) * 8;
  const int srow = tid >> 3;
  const int scol = (tid & 7) * 4;

  for (int k0 = 0; k0 < 512; k0 += 32) {
    __syncthreads();
#pragma unroll
    for (int p = 0; p < 2; ++p) {
      int row = p * 64 + arow;
      short8 av = ld8(&A[(size_t)(m0 + row) * 512 + k0 + acol]);
      *reinterpret_cast<short8*>(&Al[row][acol]) = av;
    }
#pragma unroll
    for (int p = 0; p < 4; ++p) {
      int row = p * 32 + srow;
      f32x4 wv = *reinterpret_cast<const f32x4*>(&W[(size_t)(n0 + row) * 512 + k0 + scol]);
      u16x4 wb = { f2bf(wv[0]), f2bf(wv[1]), f2bf(wv[2]), f2bf(wv[3]) };
      *reinterpret_cast<u16x4*>(&Bl[row][scol]) = wb;
    }
    __syncthreads();
    short8 af[4], bfr[4];
#pragma unroll
    for (int i = 0; i < 4; ++i) {
      af[i]  = ld8(&Al[wm + i * 16 + c][g * 8]);
      bfr[i] = ld8(&Bl[wn + i * 16 + c][g * 8]);
    }
#pragma unroll
    for (int i = 0; i < 4; ++i)
#pragma unroll
      for (int j = 0; j < 4; ++j)
        acc[i][j] = __builtin_amdgcn_mfma_f32_16x16x32_bf16(af[i], bfr[j], acc[i][j], 0, 0, 0);
  }

#pragma unroll
  for (int j = 0; j < 4; ++j) {
    int col = n0 + wn + j * 16 + c;
    float bcol = bias[col];
#pragma unroll
    for (int i = 0; i < 4; ++i)
#pragma unroll
      for (int r = 0; r < 4; ++r) {
        int row = m0 + wm + i * 16 + g * 4 + r;
        out[(size_t)row * 512 + col] = acc[i][j][r] + bcol;
      }
  }
}

extern "C" void kernel_launch(void* const* d_in, const int* in_sizes, int n_in,
                              void* d_out, int out_size, void* d_ws, size_t ws_size,
                              hipStream_t stream)
{
  const float* q  = (const float*)d_in[0];
  const float* k  = (const float*)d_in[1];
  const float* v  = (const float*)d_in[2];
  const float* Wq = (const float*)d_in[3];
  const float* bq = (const float*)d_in[4];
  const float* Wk = (const float*)d_in[5];
  const float* bk = (const float*)d_in[6];
  const float* Wv = (const float*)d_in[7];
  const float* bv = (const float*)d_in[8];
  const float* Wo = (const float*)d_in[9];
  const float* bo = (const float*)d_in[10];
  float* out = (float*)d_out;

  unsigned short* ws = (unsigned short*)d_ws;
  unsigned short* Qh = ws;                              // [32][2048][64] (pre-scaled log2e/8)
  unsigned short* Kh = ws + (size_t)4 * 1024 * 1024;    // [32][2048][64]
  unsigned short* Vt = ws + (size_t)8 * 1024 * 1024;    // [32][64][2048]
  unsigned short* at = ws + (size_t)12 * 1024 * 1024;   // [4][2048][512]

  dim3 blk(256);
  proj3<<<dim3(64, 4, 3), blk, 0, stream>>>(q, k, v, Wq, Wk, Wv, bq, bk, bv, Qh, Kh, Vt);
  flash_attn<<<dim3(64, 32), blk, 0, stream>>>(Qh, Kh, Vt, at);
  out_gemm<<<dim3(64, 4), blk, 0, stream>>>(at, Wo, bo, out);
}